// Round 19
// baseline (84.391 us; speedup 1.0000x reference)
//
#include <hip/hip_runtime.h>
#include <hip/hip_bf16.h>

typedef __attribute__((ext_vector_type(8))) short short8;
typedef __attribute__((ext_vector_type(4))) float f32x4;

#define PIX  196
#define EPSN 1e-5f

// ---------------- ws byte layout (~20.85 MB, proven size) ----------------
#define BO_XQ   256                      // [32][196][1024] bf16; REUSED by conv3 as pre-GN bf16 [32][1024][196]
#define BO_H1Q  (BO_XQ + 12845056)       // [32][196][256] bf16
#define BO_H2Q  (BO_H1Q + 3211264)
#define BO_W1Q  (BO_H2Q + 3211264)       // [3][256][1024] bf16 = 1,572,864 B
#define BO_GNS  (BO_W1Q + 1572864)       // [32][4][8][2] f32 = 8 KB
#define BO_PMAX (BO_GNS + 8192)          // [3][48] f32
// ---------------- d_out scratch (dead until gn_apply writes it) ----------------
#define DO_W2Q  0                        // [3][9][256][256] bf16 = 3,538,944 B
#define DO_W3Q  3538944                  // [3][1024][256] bf16 = 1,572,864 B

__device__ __forceinline__ float e_ascale(int e) { return e == 0 ? 3.f : (e == 1 ? 15.f : 255.f); }
__device__ __forceinline__ float e_nq(int e)     { return e == 0 ? 1.f : (e == 1 ? 7.f : 127.f); }

__device__ __forceinline__ f32x4 mfma16(short8 a, short8 b, f32x4 c) {
    return __builtin_amdgcn_mfma_f32_16x16x32_bf16(a, b, c, 0, 0, 0);
}
__device__ __forceinline__ float wmax_reduce(const char* wsb, int t) {
    const float* pm = (const float*)(wsb + BO_PMAX) + t * 48;
    float s = 0.f;
    #pragma unroll
    for (int k = 0; k < 48; ++k) s = fmaxf(s, pm[k]);
    return s + 1e-12f;
}
__device__ __forceinline__ float bf16s_to_f32(short h) {
    unsigned u = ((unsigned)(unsigned short)h) << 16;
    return __uint_as_float(u);
}

// ---------------- k1: max|w| partials [3][48], float4 + 1024 thr ----------------
__global__ __launch_bounds__(1024) void maxabs_kernel(
        const float* __restrict__ w1, const float* __restrict__ w2,
        const float* __restrict__ w3, float* __restrict__ pmax) {
    int t = blockIdx.x / 48, j = blockIdx.x - t * 48;
    const float4* w4 = (const float4*)(t == 0 ? w1 : (t == 1 ? w2 : w3));
    int n4 = (t == 1) ? 147456 : 65536;
    float m = 0.f;
    for (int i = j * 1024 + threadIdx.x; i < n4; i += 48 * 1024) {
        float4 v = w4[i];
        m = fmaxf(m, fmaxf(fmaxf(fabsf(v.x), fabsf(v.y)), fmaxf(fabsf(v.z), fabsf(v.w))));
    }
    __shared__ float red[1024];
    red[threadIdx.x] = m;
    __syncthreads();
    for (int s = 512; s > 0; s >>= 1) {
        if (threadIdx.x < s) red[threadIdx.x] = fmaxf(red[threadIdx.x], red[threadIdx.x + s]);
        __syncthreads();
    }
    if (threadIdx.x == 0) pmax[t * 48 + j] = red[0];
}

// ---------------- k2: ALL preps fused (x->xq, w1q->ws, w2q/w3q->d_out) — r12 proven form ----------------
// grid 4864: [0,512)=xprep, [512,1536)=w1q, [1536,3840)=w2q, [3840,4864)=w3q
__global__ __launch_bounds__(256) void prep_all(
        const float* __restrict__ w1, const float* __restrict__ w2,
        const float* __restrict__ w3, const float* __restrict__ x,
        const int* __restrict__ mask, char* wsb, char* doutb) {
    __shared__ float xs[64][197];
    int tid = threadIdx.x, bx = blockIdx.x;
    if (bx < 512) {
        int b = bx >> 4, c0 = (bx & 15) * 64;
        float ascale = e_ascale(mask[b]);
        for (int idx = tid; idx < 64 * 196; idx += 256) {
            int ci = idx / 196, p = idx - ci * 196;
            xs[ci][p] = x[((size_t)b * 1024 + c0 + ci) * 196 + p];
        }
        __syncthreads();
        __hip_bfloat16* xq = (__hip_bfloat16*)(wsb + BO_XQ);
        for (int idx = tid; idx < 196 * 64; idx += 256) {
            int p = idx / 64, ci = idx - p * 64;
            float v = fminf(fmaxf(xs[ci][p], 0.f), 1.f);
            xq[((size_t)b * 196 + p) * 1024 + c0 + ci] = __float2bfloat16(rintf(v * ascale));
        }
    } else if (bx < 1536) {
        int idx = (bx - 512) * 256 + tid;                // 262144
        float s = wmax_reduce(wsb, 0);
        float v = w1[idx];
        __hip_bfloat16* dst = (__hip_bfloat16*)(wsb + BO_W1Q);
        #pragma unroll
        for (int e = 0; e < 3; ++e)
            dst[e * 262144 + idx] = __float2bfloat16(rintf(v / s * e_nq(e)));
    } else if (bx < 3840) {
        int idx = (bx - 1536) * 256 + tid;               // 589824
        float s = wmax_reduce(wsb, 1);
        float v = w2[idx];
        int co = idx / 2304, r = idx - co * 2304, ci = r / 9, tap = r - ci * 9;
        __hip_bfloat16* dst = (__hip_bfloat16*)(doutb + DO_W2Q);
        size_t off = ((size_t)tap * 256 + co) * 256 + ci;
        #pragma unroll
        for (int e = 0; e < 3; ++e)
            dst[e * 589824 + off] = __float2bfloat16(rintf(v / s * e_nq(e)));
    } else {
        int idx = (bx - 3840) * 256 + tid;               // 262144
        float s = wmax_reduce(wsb, 2);
        float v = w3[idx];
        __hip_bfloat16* dst = (__hip_bfloat16*)(doutb + DO_W3Q);
        #pragma unroll
        for (int e = 0; e < 3; ++e)
            dst[e * 262144 + idx] = __float2bfloat16(rintf(v / s * e_nq(e)));
    }
}

// ================= conv1: 1x1 1024->256 + BN1 + ReLU + qact — M112 x N64, wave 4Mx2N, BK=128 =================
// grid (2 M(112px), 4 N(64co), 32) = 256 blocks. LDS 47.9 KB. 4 waves = 2Mh(56px) x 2Nh(32co).
// Per ks: 6 ds_reads feed 8 MFMAs (21.8 FLOP/B vs old 16.4); global staging per sample halves.
__global__ __launch_bounds__(256) void conv1_mfma(
        char* wsb, const int* __restrict__ mask,
        const float* __restrict__ bg, const float* __restrict__ bb,
        const float* __restrict__ bm, const float* __restrict__ bv) {
    int b = blockIdx.z;
    int e = mask[b];
    float ascale = e_ascale(e);
    float s1 = wmax_reduce(wsb, 0);
    float kscale = (s1 / e_nq(e)) / ascale;

    const short* xq  = (const short*)(wsb + BO_XQ) + (size_t)b * 196 * 1024;
    const short* w1q = (const short*)(wsb + BO_W1Q) + (size_t)e * 262144;
    __hip_bfloat16* h1q = (__hip_bfloat16*)(wsb + BO_H1Q) + (size_t)b * 196 * 256;

    __shared__ short As[112 * 136];   // 30,464 B
    __shared__ short Bs[64 * 136];    // 17,408 B

    int tid = threadIdx.x, w = tid >> 6, lane = tid & 63, r15 = lane & 15, g = lane >> 4;
    int mh = w >> 1, nh = w & 1;
    int px0 = blockIdx.x * 112, coB = blockIdx.y * 64;

    short8 ra[7], rb[4];
    auto load_tile = [&](int t) {
        int k0 = t * 128;
        #pragma unroll
        for (int ii = 0; ii < 7; ++ii) {             // A: 112*16 = 1792 chunks
            int idx = ii * 256 + tid;
            int row = idx >> 4, c8 = (idx & 15) * 8;
            ra[ii] = *(const short8*)(xq + (size_t)min(px0 + row, 195) * 1024 + k0 + c8);
        }
        #pragma unroll
        for (int ii = 0; ii < 4; ++ii) {             // B: 64*16 = 1024 chunks
            int idx = ii * 256 + tid;
            int row = idx >> 4, c8 = (idx & 15) * 8;
            rb[ii] = *(const short8*)(w1q + (size_t)(coB + row) * 1024 + k0 + c8);
        }
    };
    auto store_tile = [&]() {
        #pragma unroll
        for (int ii = 0; ii < 7; ++ii) {
            int idx = ii * 256 + tid;
            *(short8*)(As + (idx >> 4) * 136 + (idx & 15) * 8) = ra[ii];
        }
        #pragma unroll
        for (int ii = 0; ii < 4; ++ii) {
            int idx = ii * 256 + tid;
            *(short8*)(Bs + (idx >> 4) * 136 + (idx & 15) * 8) = rb[ii];
        }
    };

    f32x4 acc[4][2] = {};
    load_tile(0);
    for (int t = 0; t < 8; ++t) {
        __syncthreads();
        store_tile();
        __syncthreads();
        if (t < 7) load_tile(t + 1);
        #pragma unroll
        for (int ks = 0; ks < 4; ++ks) {
            short8 bf0 = *(const short8*)(Bs + (nh * 32 + r15) * 136 + ks * 32 + g * 8);
            short8 bf1 = *(const short8*)(Bs + (nh * 32 + 16 + r15) * 136 + ks * 32 + g * 8);
            #pragma unroll
            for (int m = 0; m < 4; ++m) {
                int arow = min(mh * 56 + m * 16 + r15, 111);
                short8 af = *(const short8*)(As + arow * 136 + ks * 32 + g * 8);
                acc[m][0] = mfma16(af, bf0, acc[m][0]);
                acc[m][1] = mfma16(af, bf1, acc[m][1]);
            }
        }
    }
    #pragma unroll
    for (int n = 0; n < 2; ++n) {
        int co = coB + nh * 32 + n * 16 + r15;
        float inv = bg[co] * rsqrtf(bv[co] + EPSN);
        float mm = kscale * inv;
        float beta = bb[co] - bm[co] * inv;
        #pragma unroll
        for (int m = 0; m < 4; ++m)
            #pragma unroll
            for (int r = 0; r < 4; ++r) {
                int sm = m * 16 + g * 4 + r;             // local within 56-px half
                int px = px0 + mh * 56 + sm;
                if (sm < 56 && px < 196) {
                    float h = fmaxf(acc[m][n][r] * mm + beta, 0.f);
                    h1q[(size_t)px * 256 + co] = __float2bfloat16(rintf(fminf(h, 1.f) * ascale));
                }
            }
    }
}

// ================= conv2: 3x3 256->256 + BN2 + ReLU + qact — M112 x N64, wave 4Mx2N (r18 champion) =================
// grid (2 M(8 rows = 112px), 4 N(64co), 32) = 256 blocks. LDS 58,880 B.
__global__ __launch_bounds__(256) void conv2_mfma(
        char* wsb, const char* __restrict__ doutb, const int* __restrict__ mask,
        const float* __restrict__ bg, const float* __restrict__ bb,
        const float* __restrict__ bm, const float* __restrict__ bv) {
    int b = blockIdx.z;
    int e = mask[b];
    float ascale = e_ascale(e);
    float s2 = wmax_reduce(wsb, 1);
    float kscale = (s2 / e_nq(e)) / ascale;

    const short* h1q = (const short*)(wsb + BO_H1Q) + (size_t)b * 196 * 256;
    const short* w2q = (const short*)(doutb + DO_W2Q) + (size_t)e * 589824;
    __hip_bfloat16* h2q = (__hip_bfloat16*)(wsb + BO_H2Q) + (size_t)b * 196 * 256;

    __shared__ short Xs[10 * 16 * 40];   // rows r0-1..r0+8, cols -1..14, 32ci (stride 40) = 12.8 KB
    __shared__ short Ws9[9 * 64 * 40];   // [tap][co][32ci] (stride 40) = 46 KB

    int tid = threadIdx.x, w = tid >> 6, lane = tid & 63, r15 = lane & 15, g = lane >> 4;
    int mh = w >> 1, nh = w & 1;
    int r0 = blockIdx.x * 8;
    int px0 = blockIdx.x * 112;
    int coB = blockIdx.y * 64;
    const short8 z8 = {0, 0, 0, 0, 0, 0, 0, 0};

    int wco = tid >> 2, wc8 = (tid & 3) * 8;

    int rr[4], cc[4];
    #pragma unroll
    for (int m = 0; m < 4; ++m) {
        int s0 = min(mh * 56 + m * 16 + r15, 111);
        rr[m] = s0 / 14; cc[m] = s0 - rr[m] * 14;    // local row 0..7 within block
    }

    short8 rx[3], rw[9];
    auto load_tile = [&](int sl) {
        int ci0 = sl * 32;
        #pragma unroll
        for (int ii = 0; ii < 3; ++ii) {             // X: 10*16*4 = 640 chunks
            int idx = ii * 256 + tid;
            rx[ii] = z8;
            if (idx < 640) {
                int xc = idx & 3, xsx = (idx >> 2) & 15, xsy = idx >> 6;
                int iy = r0 - 1 + xsy, ix = xsx - 1;
                if ((unsigned)iy < 14u && (unsigned)ix < 14u)
                    rx[ii] = *(const short8*)(h1q + (size_t)(iy * 14 + ix) * 256 + ci0 + xc * 8);
            }
        }
        #pragma unroll
        for (int tap = 0; tap < 9; ++tap)            // W: 9*64*4 = 2304 chunks
            rw[tap] = *(const short8*)(w2q + ((size_t)tap * 256 + coB + wco) * 256 + ci0 + wc8);
    };
    auto store_tile = [&]() {
        #pragma unroll
        for (int ii = 0; ii < 3; ++ii) {
            int idx = ii * 256 + tid;
            if (idx < 640) {
                int xc = idx & 3, xsx = (idx >> 2) & 15, xsy = idx >> 6;
                *(short8*)(Xs + (xsy * 16 + xsx) * 40 + xc * 8) = rx[ii];
            }
        }
        #pragma unroll
        for (int tap = 0; tap < 9; ++tap)
            *(short8*)(Ws9 + (tap * 64 + wco) * 40 + wc8) = rw[tap];
    };

    f32x4 acc[4][2] = {};
    load_tile(0);
    for (int sl = 0; sl < 8; ++sl) {
        __syncthreads();
        store_tile();
        __syncthreads();
        if (sl < 7) load_tile(sl + 1);
        #pragma unroll
        for (int tap = 0; tap < 9; ++tap) {
            int ty = tap / 3, tx = tap - ty * 3;
            short8 bf0 = *(const short8*)(Ws9 + (tap * 64 + nh * 32 + r15) * 40 + g * 8);
            short8 bf1 = *(const short8*)(Ws9 + (tap * 64 + nh * 32 + 16 + r15) * 40 + g * 8);
            #pragma unroll
            for (int m = 0; m < 4; ++m) {
                short8 af = *(const short8*)(Xs + ((rr[m] + ty) * 16 + cc[m] + tx) * 40 + g * 8);
                acc[m][0] = mfma16(af, bf0, acc[m][0]);
                acc[m][1] = mfma16(af, bf1, acc[m][1]);
            }
        }
    }
    #pragma unroll
    for (int n = 0; n < 2; ++n) {
        int co = coB + nh * 32 + n * 16 + r15;
        float inv = bg[co] * rsqrtf(bv[co] + EPSN);
        float mm = kscale * inv;
        float beta = bb[co] - bm[co] * inv;
        #pragma unroll
        for (int m = 0; m < 4; ++m)
            #pragma unroll
            for (int r = 0; r < 4; ++r) {
                int s = mh * 56 + m * 16 + g * 4 + r, px = px0 + s;
                if (s < 112 && px < 196) {
                    float h = fmaxf(acc[m][n][r] * mm + beta, 0.f);
                    h2q[(size_t)px * 256 + co] = __float2bfloat16(rintf(fminf(h, 1.f) * ascale));
                }
            }
    }
}

// ================= conv3: 1x1 256->1024 -> bf16 pre-GN (ws) + GN partials =================
// grid (4 M(56px), 8 N(128co), 32). wave = 4M x 2N frags. BK=64.
__global__ __launch_bounds__(256) void conv3_mfma(
        char* wsb, const char* __restrict__ doutb, const int* __restrict__ mask) {
    int b = blockIdx.z;
    int e = mask[b];
    float ascale = e_ascale(e);
    float s3 = wmax_reduce(wsb, 2);
    float kscale = (s3 / e_nq(e)) / ascale;

    const short* h2q = (const short*)(wsb + BO_H2Q) + (size_t)b * 196 * 256;
    const short* w3q = (const short*)(doutb + DO_W3Q) + (size_t)e * 262144;
    __hip_bfloat16* pg = (__hip_bfloat16*)(wsb + BO_XQ) + (size_t)b * 1024 * 196;  // pre-GN NCHW bf16

    __shared__ float Ct[128 * 58];       // 29,696 B; aliased by As|Bs (27,648 B)
    __shared__ float rs[256], rss[256];
    short* As = (short*)Ct;              // 64*72 shorts
    short* Bs = As + 64 * 72;            // 128*72 shorts

    int tid = threadIdx.x, w = tid >> 6, lane = tid & 63, r15 = lane & 15, g = lane >> 4;
    int px0 = blockIdx.x * 56;
    int coQ = blockIdx.y * 128;
    int gslot = (b * 4 + (blockIdx.y >> 1)) * 8 + (blockIdx.y & 1) * 4 + blockIdx.x;

    short8 ra[2], rb[4];
    auto load_tile = [&](int t) {
        int k0 = t * 64;
        #pragma unroll
        for (int ii = 0; ii < 2; ++ii) {
            int idx = ii * 256 + tid;
            int arow = idx >> 3, ac = (idx & 7) * 8;
            ra[ii] = *(const short8*)(h2q + (size_t)min(px0 + arow, 195) * 256 + k0 + ac);
        }
        #pragma unroll
        for (int ii = 0; ii < 4; ++ii) {
            int idx = ii * 256 + tid;
            int brow = idx >> 3, bc = (idx & 7) * 8;
            rb[ii] = *(const short8*)(w3q + (size_t)(coQ + brow) * 256 + k0 + bc);
        }
    };
    auto store_tile = [&]() {
        #pragma unroll
        for (int ii = 0; ii < 2; ++ii) {
            int idx = ii * 256 + tid;
            *(short8*)(As + (idx >> 3) * 72 + (idx & 7) * 8) = ra[ii];
        }
        #pragma unroll
        for (int ii = 0; ii < 4; ++ii) {
            int idx = ii * 256 + tid;
            *(short8*)(Bs + (idx >> 3) * 72 + (idx & 7) * 8) = rb[ii];
        }
    };

    f32x4 acc[4][2] = {};
    load_tile(0);
    for (int t = 0; t < 4; ++t) {
        __syncthreads();
        store_tile();
        __syncthreads();
        if (t < 3) load_tile(t + 1);
        #pragma unroll
        for (int ks = 0; ks < 2; ++ks) {
            short8 bf0 = *(const short8*)(Bs + (w * 32 + r15) * 72 + ks * 32 + g * 8);
            short8 bf1 = *(const short8*)(Bs + (w * 32 + 16 + r15) * 72 + ks * 32 + g * 8);
            #pragma unroll
            for (int m = 0; m < 4; ++m) {
                short8 af = *(const short8*)(As + (m * 16 + r15) * 72 + ks * 32 + g * 8);
                acc[m][0] = mfma16(af, bf0, acc[m][0]);
                acc[m][1] = mfma16(af, bf1, acc[m][1]);
            }
        }
    }
    __syncthreads();                     // all As/Bs reads complete before Ct overwrite
    #pragma unroll
    for (int n = 0; n < 2; ++n)
        #pragma unroll
        for (int m = 0; m < 4; ++m)
            #pragma unroll
            for (int r = 0; r < 4; ++r) {
                int s = m * 16 + g * 4 + r;
                if (s < 56) Ct[(w * 32 + n * 16 + r15) * 58 + s] = acc[m][n][r];
            }
    __syncthreads();
    float sum = 0.f, ss = 0.f;
    for (int idx = tid; idx < 128 * 56; idx += 256) {
        int col = idx / 56, s = idx - col * 56, px = px0 + s;
        if (px < 196) {
            float v = Ct[col * 58 + s] * kscale;
            __hip_bfloat16 hv = __float2bfloat16(v);
            float vq = __bfloat162float(hv);
            pg[(size_t)(coQ + col) * 196 + px] = hv;
            sum += vq; ss += vq * vq;    // stats over exactly what gn_apply will read
        }
    }
    rs[tid] = sum; rss[tid] = ss;
    __syncthreads();
    for (int st = 128; st > 0; st >>= 1) {
        if (tid < st) { rs[tid] += rs[tid + st]; rss[tid] += rss[tid + st]; }
        __syncthreads();
    }
    if (tid == 0) {
        float* gns = (float*)(wsb + BO_GNS);
        gns[gslot * 2] = rs[0];
        gns[gslot * 2 + 1] = rss[0];
    }
}

// ---------------- gn_apply: bf16 pre-GN + residual -> f32 d_out ----------------
__global__ __launch_bounds__(256) void gn_apply(
        const char* __restrict__ wsb, const float* __restrict__ x,
        const float* __restrict__ gg, const float* __restrict__ gb,
        float* __restrict__ out) {
    int bgid = blockIdx.x >> 4, six = blockIdx.x & 15;
    int g = bgid & 3;
    const float* gns = (const float*)(wsb + BO_GNS);
    float S = 0.f, Q = 0.f;
    #pragma unroll
    for (int k = 0; k < 8; ++k) { S += gns[(bgid * 8 + k) * 2]; Q += gns[(bgid * 8 + k) * 2 + 1]; }
    float mu = S * (1.f / 50176.f);
    float var = Q * (1.f / 50176.f) - mu * mu;
    float rstd = rsqrtf(var + EPSN);

    const __hip_bfloat16* pg = (const __hip_bfloat16*)(wsb + BO_XQ) + (size_t)bgid * 50176;
    const float* xg = x + (size_t)bgid * 50176;
    float* og = out + (size_t)bgid * 50176;

    int tid = threadIdx.x;
    for (int i = tid; i < 392; i += 256) {           // 3136 elems per section, 8/thread
        int eb = six * 3136 + i * 8;
        int c = eb / 196, r = eb - c * 196;
        short8 hv = *(const short8*)(pg + eb);
        float4 x0 = *(const float4*)(xg + eb);
        float4 x1 = *(const float4*)(xg + eb + 4);
        float xv[8] = {x0.x, x0.y, x0.z, x0.w, x1.x, x1.y, x1.z, x1.w};
        float o[8];
        #pragma unroll
        for (int j = 0; j < 8; ++j) {
            int gc = g * 256 + c;
            float sc = gg[gc] * rstd;
            float sh = gb[gc] - mu * sc;
            float v = bf16s_to_f32(hv[j]);
            o[j] = fmaxf(v * sc + sh + xv[j], 0.f);
            if (++r == 196) { r = 0; ++c; }
        }
        *(float4*)(og + eb)     = make_float4(o[0], o[1], o[2], o[3]);
        *(float4*)(og + eb + 4) = make_float4(o[4], o[5], o[6], o[7]);
    }
}

// ---------------- launch ----------------
extern "C" void kernel_launch(void* const* d_in, const int* in_sizes, int n_in,
                              void* d_out, int out_size, void* d_ws, size_t ws_size,
                              hipStream_t stream) {
    (void)in_sizes; (void)n_in; (void)out_size; (void)ws_size;
    const float* x    = (const float*)d_in[0];
    const int*   mask = (const int*)d_in[1];
    const float* w1   = (const float*)d_in[2];
    const float* w2   = (const float*)d_in[3];
    const float* w3   = (const float*)d_in[4];
    const float* b1g  = (const float*)d_in[5];
    const float* b1b  = (const float*)d_in[6];
    const float* b1m  = (const float*)d_in[7];
    const float* b1v  = (const float*)d_in[8];
    const float* b2g  = (const float*)d_in[9];
    const float* b2b  = (const float*)d_in[10];
    const float* b2m  = (const float*)d_in[11];
    const float* b2v  = (const float*)d_in[12];
    const float* gng  = (const float*)d_in[13];
    const float* gnb  = (const float*)d_in[14];
    char* wsb = (char*)d_ws;
    char* doutb = (char*)d_out;
    float* out = (float*)d_out;

    maxabs_kernel<<<144, 1024, 0, stream>>>(w1, w2, w3, (float*)(wsb + BO_PMAX));
    prep_all<<<4864, 256, 0, stream>>>(w1, w2, w3, x, mask, wsb, doutb);
    conv1_mfma<<<dim3(2, 4, 32), 256, 0, stream>>>(wsb, mask, b1g, b1b, b1m, b1v);
    conv2_mfma<<<dim3(2, 4, 32), 256, 0, stream>>>(wsb, doutb, mask, b2g, b2b, b2m, b2v);
    conv3_mfma<<<dim3(4, 8, 32), 256, 0, stream>>>(wsb, doutb, mask);
    gn_apply<<<2048, 256, 0, stream>>>(wsb, x, gng, gnb, out);
}

// Round 20
// 81.366 us; speedup vs baseline: 1.0372x; 1.0372x over previous
//
#include <hip/hip_runtime.h>
#include <hip/hip_bf16.h>

typedef __attribute__((ext_vector_type(8))) short short8;
typedef __attribute__((ext_vector_type(4))) float f32x4;

#define PIX  196
#define EPSN 1e-5f

// ---------------- ws byte layout (~20.85 MB, proven size) ----------------
#define BO_XQ   256                      // [32][196][1024] bf16; REUSED by conv3 as pre-GN bf16 [32][1024][196]
#define BO_H1Q  (BO_XQ + 12845056)       // [32][196][256] bf16
#define BO_H2Q  (BO_H1Q + 3211264)
#define BO_W1Q  (BO_H2Q + 3211264)       // [3][256][1024] bf16 = 1,572,864 B
#define BO_GNS  (BO_W1Q + 1572864)       // [32][4][8][2] f32 = 8 KB
#define BO_PMAX (BO_GNS + 8192)          // [3][48] f32
// ---------------- d_out scratch (dead until gn_apply writes it) ----------------
#define DO_W2Q  0                        // [3][9][256][256] bf16 = 3,538,944 B
#define DO_W3Q  3538944                  // [3][1024][256] bf16 = 1,572,864 B

__device__ __forceinline__ float e_ascale(int e) { return e == 0 ? 3.f : (e == 1 ? 15.f : 255.f); }
__device__ __forceinline__ float e_nq(int e)     { return e == 0 ? 1.f : (e == 1 ? 7.f : 127.f); }

__device__ __forceinline__ f32x4 mfma16(short8 a, short8 b, f32x4 c) {
    return __builtin_amdgcn_mfma_f32_16x16x32_bf16(a, b, c, 0, 0, 0);
}
__device__ __forceinline__ float wmax_reduce(const char* wsb, int t) {
    const float* pm = (const float*)(wsb + BO_PMAX) + t * 48;
    float s = 0.f;
    #pragma unroll
    for (int k = 0; k < 48; ++k) s = fmaxf(s, pm[k]);
    return s + 1e-12f;
}
__device__ __forceinline__ float bf16s_to_f32(short h) {
    unsigned u = ((unsigned)(unsigned short)h) << 16;
    return __uint_as_float(u);
}

// ---------------- k1: max|w| partials [3][48], float4 + 1024 thr ----------------
__global__ __launch_bounds__(1024) void maxabs_kernel(
        const float* __restrict__ w1, const float* __restrict__ w2,
        const float* __restrict__ w3, float* __restrict__ pmax) {
    int t = blockIdx.x / 48, j = blockIdx.x - t * 48;
    const float4* w4 = (const float4*)(t == 0 ? w1 : (t == 1 ? w2 : w3));
    int n4 = (t == 1) ? 147456 : 65536;
    float m = 0.f;
    for (int i = j * 1024 + threadIdx.x; i < n4; i += 48 * 1024) {
        float4 v = w4[i];
        m = fmaxf(m, fmaxf(fmaxf(fabsf(v.x), fabsf(v.y)), fmaxf(fabsf(v.z), fabsf(v.w))));
    }
    __shared__ float red[1024];
    red[threadIdx.x] = m;
    __syncthreads();
    for (int s = 512; s > 0; s >>= 1) {
        if (threadIdx.x < s) red[threadIdx.x] = fmaxf(red[threadIdx.x], red[threadIdx.x + s]);
        __syncthreads();
    }
    if (threadIdx.x == 0) pmax[t * 48 + j] = red[0];
}

// ---------------- k2: ALL preps fused (x->xq, w1q->ws, w2q/w3q->d_out) — r12 proven form ----------------
// grid 4864: [0,512)=xprep, [512,1536)=w1q, [1536,3840)=w2q, [3840,4864)=w3q
__global__ __launch_bounds__(256) void prep_all(
        const float* __restrict__ w1, const float* __restrict__ w2,
        const float* __restrict__ w3, const float* __restrict__ x,
        const int* __restrict__ mask, char* wsb, char* doutb) {
    __shared__ float xs[64][197];
    int tid = threadIdx.x, bx = blockIdx.x;
    if (bx < 512) {
        int b = bx >> 4, c0 = (bx & 15) * 64;
        float ascale = e_ascale(mask[b]);
        for (int idx = tid; idx < 64 * 196; idx += 256) {
            int ci = idx / 196, p = idx - ci * 196;
            xs[ci][p] = x[((size_t)b * 1024 + c0 + ci) * 196 + p];
        }
        __syncthreads();
        __hip_bfloat16* xq = (__hip_bfloat16*)(wsb + BO_XQ);
        for (int idx = tid; idx < 196 * 64; idx += 256) {
            int p = idx / 64, ci = idx - p * 64;
            float v = fminf(fmaxf(xs[ci][p], 0.f), 1.f);
            xq[((size_t)b * 196 + p) * 1024 + c0 + ci] = __float2bfloat16(rintf(v * ascale));
        }
    } else if (bx < 1536) {
        int idx = (bx - 512) * 256 + tid;                // 262144
        float s = wmax_reduce(wsb, 0);
        float v = w1[idx];
        __hip_bfloat16* dst = (__hip_bfloat16*)(wsb + BO_W1Q);
        #pragma unroll
        for (int e = 0; e < 3; ++e)
            dst[e * 262144 + idx] = __float2bfloat16(rintf(v / s * e_nq(e)));
    } else if (bx < 3840) {
        int idx = (bx - 1536) * 256 + tid;               // 589824
        float s = wmax_reduce(wsb, 1);
        float v = w2[idx];
        int co = idx / 2304, r = idx - co * 2304, ci = r / 9, tap = r - ci * 9;
        __hip_bfloat16* dst = (__hip_bfloat16*)(doutb + DO_W2Q);
        size_t off = ((size_t)tap * 256 + co) * 256 + ci;
        #pragma unroll
        for (int e = 0; e < 3; ++e)
            dst[e * 589824 + off] = __float2bfloat16(rintf(v / s * e_nq(e)));
    } else {
        int idx = (bx - 3840) * 256 + tid;               // 262144
        float s = wmax_reduce(wsb, 2);
        float v = w3[idx];
        __hip_bfloat16* dst = (__hip_bfloat16*)(doutb + DO_W3Q);
        #pragma unroll
        for (int e = 0; e < 3; ++e)
            dst[e * 262144 + idx] = __float2bfloat16(rintf(v / s * e_nq(e)));
    }
}

// ================= conv1: 1x1 1024->256 + BN1 + ReLU + qact, BK=128 (r13/r14-verified) =================
// grid (4 M(56px), 4 N(64co), 32) = 512 blocks. 34.8 KB LDS. 4 waves = 2Mh x 2Nh.
__global__ __launch_bounds__(256) void conv1_mfma(
        char* wsb, const int* __restrict__ mask,
        const float* __restrict__ bg, const float* __restrict__ bb,
        const float* __restrict__ bm, const float* __restrict__ bv) {
    int b = blockIdx.z;
    int e = mask[b];
    float ascale = e_ascale(e);
    float s1 = wmax_reduce(wsb, 0);
    float kscale = (s1 / e_nq(e)) / ascale;

    const short* xq  = (const short*)(wsb + BO_XQ) + (size_t)b * 196 * 1024;
    const short* w1q = (const short*)(wsb + BO_W1Q) + (size_t)e * 262144;
    __hip_bfloat16* h1q = (__hip_bfloat16*)(wsb + BO_H1Q) + (size_t)b * 196 * 256;

    __shared__ short As[64 * 136];
    __shared__ short Bs[64 * 136];

    int tid = threadIdx.x, w = tid >> 6, lane = tid & 63, r15 = lane & 15, g = lane >> 4;
    int mh = w >> 1, nh = w & 1;
    int px0 = blockIdx.x * 56, coB = blockIdx.y * 64;

    short8 ra[4], rb[4];
    auto load_tile = [&](int t) {
        int k0 = t * 128;
        #pragma unroll
        for (int ii = 0; ii < 4; ++ii) {
            int idx = ii * 256 + tid;
            int row = idx >> 4, c8 = (idx & 15) * 8;
            ra[ii] = *(const short8*)(xq + (size_t)min(px0 + row, 195) * 1024 + k0 + c8);
            rb[ii] = *(const short8*)(w1q + (size_t)(coB + row) * 1024 + k0 + c8);
        }
    };
    auto store_tile = [&]() {
        #pragma unroll
        for (int ii = 0; ii < 4; ++ii) {
            int idx = ii * 256 + tid;
            int row = idx >> 4, c8 = (idx & 15) * 8;
            *(short8*)(As + row * 136 + c8) = ra[ii];
            *(short8*)(Bs + row * 136 + c8) = rb[ii];
        }
    };

    f32x4 acc[2][2] = {};
    load_tile(0);
    for (int t = 0; t < 8; ++t) {
        __syncthreads();
        store_tile();
        __syncthreads();
        if (t < 7) load_tile(t + 1);
        #pragma unroll
        for (int ks = 0; ks < 4; ++ks) {
            short8 bf0 = *(const short8*)(Bs + (nh * 32 + r15) * 136 + ks * 32 + g * 8);
            short8 bf1 = *(const short8*)(Bs + (nh * 32 + 16 + r15) * 136 + ks * 32 + g * 8);
            #pragma unroll
            for (int m = 0; m < 2; ++m) {
                short8 af = *(const short8*)(As + (mh * 32 + m * 16 + r15) * 136 + ks * 32 + g * 8);
                acc[m][0] = mfma16(af, bf0, acc[m][0]);
                acc[m][1] = mfma16(af, bf1, acc[m][1]);
            }
        }
    }
    #pragma unroll
    for (int n = 0; n < 2; ++n) {
        int co = coB + nh * 32 + n * 16 + r15;
        float inv = bg[co] * rsqrtf(bv[co] + EPSN);
        float mm = kscale * inv;
        float beta = bb[co] - bm[co] * inv;
        #pragma unroll
        for (int m = 0; m < 2; ++m)
            #pragma unroll
            for (int r = 0; r < 4; ++r) {
                int s = mh * 32 + m * 16 + g * 4 + r, px = px0 + s;
                if (s < 56 && px < 196) {
                    float h = fmaxf(acc[m][n][r] * mm + beta, 0.f);
                    h1q[(size_t)px * 256 + co] = __float2bfloat16(rintf(fminf(h, 1.f) * ascale));
                }
            }
    }
}

// ================= conv2: 3x3 256->256 + BN2 + ReLU + qact — M112 x N64, wave 4Mx2N (r18 champion) =================
// grid (2 M(8 rows = 112px), 4 N(64co), 32) = 256 blocks. LDS 58,880 B.
// Per tap: 6 ds_reads feed 8 MFMAs (21.8 FLOP/B) — halves total LDS read traffic vs 4Mx1N.
__global__ __launch_bounds__(256) void conv2_mfma(
        char* wsb, const char* __restrict__ doutb, const int* __restrict__ mask,
        const float* __restrict__ bg, const float* __restrict__ bb,
        const float* __restrict__ bm, const float* __restrict__ bv) {
    int b = blockIdx.z;
    int e = mask[b];
    float ascale = e_ascale(e);
    float s2 = wmax_reduce(wsb, 1);
    float kscale = (s2 / e_nq(e)) / ascale;

    const short* h1q = (const short*)(wsb + BO_H1Q) + (size_t)b * 196 * 256;
    const short* w2q = (const short*)(doutb + DO_W2Q) + (size_t)e * 589824;
    __hip_bfloat16* h2q = (__hip_bfloat16*)(wsb + BO_H2Q) + (size_t)b * 196 * 256;

    __shared__ short Xs[10 * 16 * 40];   // rows r0-1..r0+8, cols -1..14, 32ci (stride 40) = 12.8 KB
    __shared__ short Ws9[9 * 64 * 40];   // [tap][co][32ci] (stride 40) = 46 KB

    int tid = threadIdx.x, w = tid >> 6, lane = tid & 63, r15 = lane & 15, g = lane >> 4;
    int mh = w >> 1, nh = w & 1;
    int r0 = blockIdx.x * 8;
    int px0 = blockIdx.x * 112;
    int coB = blockIdx.y * 64;
    const short8 z8 = {0, 0, 0, 0, 0, 0, 0, 0};

    int wco = tid >> 2, wc8 = (tid & 3) * 8;

    int rr[4], cc[4];
    #pragma unroll
    for (int m = 0; m < 4; ++m) {
        int s0 = min(mh * 56 + m * 16 + r15, 111);
        rr[m] = s0 / 14; cc[m] = s0 - rr[m] * 14;    // local row 0..7 within block
    }

    short8 rx[3], rw[9];
    auto load_tile = [&](int sl) {
        int ci0 = sl * 32;
        #pragma unroll
        for (int ii = 0; ii < 3; ++ii) {             // X: 10*16*4 = 640 chunks
            int idx = ii * 256 + tid;
            rx[ii] = z8;
            if (idx < 640) {
                int xc = idx & 3, xsx = (idx >> 2) & 15, xsy = idx >> 6;
                int iy = r0 - 1 + xsy, ix = xsx - 1;
                if ((unsigned)iy < 14u && (unsigned)ix < 14u)
                    rx[ii] = *(const short8*)(h1q + (size_t)(iy * 14 + ix) * 256 + ci0 + xc * 8);
            }
        }
        #pragma unroll
        for (int tap = 0; tap < 9; ++tap)            // W: 9*64*4 = 2304 chunks (r14 pattern)
            rw[tap] = *(const short8*)(w2q + ((size_t)tap * 256 + coB + wco) * 256 + ci0 + wc8);
    };
    auto store_tile = [&]() {
        #pragma unroll
        for (int ii = 0; ii < 3; ++ii) {
            int idx = ii * 256 + tid;
            if (idx < 640) {
                int xc = idx & 3, xsx = (idx >> 2) & 15, xsy = idx >> 6;
                *(short8*)(Xs + (xsy * 16 + xsx) * 40 + xc * 8) = rx[ii];
            }
        }
        #pragma unroll
        for (int tap = 0; tap < 9; ++tap)
            *(short8*)(Ws9 + (tap * 64 + wco) * 40 + wc8) = rw[tap];
    };

    f32x4 acc[4][2] = {};
    load_tile(0);
    for (int sl = 0; sl < 8; ++sl) {
        __syncthreads();
        store_tile();
        __syncthreads();
        if (sl < 7) load_tile(sl + 1);
        #pragma unroll
        for (int tap = 0; tap < 9; ++tap) {
            int ty = tap / 3, tx = tap - ty * 3;
            short8 bf0 = *(const short8*)(Ws9 + (tap * 64 + nh * 32 + r15) * 40 + g * 8);
            short8 bf1 = *(const short8*)(Ws9 + (tap * 64 + nh * 32 + 16 + r15) * 40 + g * 8);
            #pragma unroll
            for (int m = 0; m < 4; ++m) {
                short8 af = *(const short8*)(Xs + ((rr[m] + ty) * 16 + cc[m] + tx) * 40 + g * 8);
                acc[m][0] = mfma16(af, bf0, acc[m][0]);
                acc[m][1] = mfma16(af, bf1, acc[m][1]);
            }
        }
    }
    #pragma unroll
    for (int n = 0; n < 2; ++n) {
        int co = coB + nh * 32 + n * 16 + r15;
        float inv = bg[co] * rsqrtf(bv[co] + EPSN);
        float mm = kscale * inv;
        float beta = bb[co] - bm[co] * inv;
        #pragma unroll
        for (int m = 0; m < 4; ++m)
            #pragma unroll
            for (int r = 0; r < 4; ++r) {
                int s = mh * 56 + m * 16 + g * 4 + r, px = px0 + s;
                if (s < 112 && px < 196) {
                    float h = fmaxf(acc[m][n][r] * mm + beta, 0.f);
                    h2q[(size_t)px * 256 + co] = __float2bfloat16(rintf(fminf(h, 1.f) * ascale));
                }
            }
    }
}

// ================= conv3: 1x1 256->1024 -> bf16 pre-GN (ws) + GN partials =================
// grid (4 M(56px), 8 N(128co), 32). wave = 4M x 2N frags. BK=64.
__global__ __launch_bounds__(256) void conv3_mfma(
        char* wsb, const char* __restrict__ doutb, const int* __restrict__ mask) {
    int b = blockIdx.z;
    int e = mask[b];
    float ascale = e_ascale(e);
    float s3 = wmax_reduce(wsb, 2);
    float kscale = (s3 / e_nq(e)) / ascale;

    const short* h2q = (const short*)(wsb + BO_H2Q) + (size_t)b * 196 * 256;
    const short* w3q = (const short*)(doutb + DO_W3Q) + (size_t)e * 262144;
    __hip_bfloat16* pg = (__hip_bfloat16*)(wsb + BO_XQ) + (size_t)b * 1024 * 196;  // pre-GN NCHW bf16

    __shared__ float Ct[128 * 58];       // 29,696 B; aliased by As|Bs (27,648 B)
    __shared__ float rs[256], rss[256];
    short* As = (short*)Ct;              // 64*72 shorts
    short* Bs = As + 64 * 72;            // 128*72 shorts

    int tid = threadIdx.x, w = tid >> 6, lane = tid & 63, r15 = lane & 15, g = lane >> 4;
    int px0 = blockIdx.x * 56;
    int coQ = blockIdx.y * 128;
    int gslot = (b * 4 + (blockIdx.y >> 1)) * 8 + (blockIdx.y & 1) * 4 + blockIdx.x;

    short8 ra[2], rb[4];
    auto load_tile = [&](int t) {
        int k0 = t * 64;
        #pragma unroll
        for (int ii = 0; ii < 2; ++ii) {
            int idx = ii * 256 + tid;
            int arow = idx >> 3, ac = (idx & 7) * 8;
            ra[ii] = *(const short8*)(h2q + (size_t)min(px0 + arow, 195) * 256 + k0 + ac);
        }
        #pragma unroll
        for (int ii = 0; ii < 4; ++ii) {
            int idx = ii * 256 + tid;
            int brow = idx >> 3, bc = (idx & 7) * 8;
            rb[ii] = *(const short8*)(w3q + (size_t)(coQ + brow) * 256 + k0 + bc);
        }
    };
    auto store_tile = [&]() {
        #pragma unroll
        for (int ii = 0; ii < 2; ++ii) {
            int idx = ii * 256 + tid;
            *(short8*)(As + (idx >> 3) * 72 + (idx & 7) * 8) = ra[ii];
        }
        #pragma unroll
        for (int ii = 0; ii < 4; ++ii) {
            int idx = ii * 256 + tid;
            *(short8*)(Bs + (idx >> 3) * 72 + (idx & 7) * 8) = rb[ii];
        }
    };

    f32x4 acc[4][2] = {};
    load_tile(0);
    for (int t = 0; t < 4; ++t) {
        __syncthreads();
        store_tile();
        __syncthreads();
        if (t < 3) load_tile(t + 1);
        #pragma unroll
        for (int ks = 0; ks < 2; ++ks) {
            short8 bf0 = *(const short8*)(Bs + (w * 32 + r15) * 72 + ks * 32 + g * 8);
            short8 bf1 = *(const short8*)(Bs + (w * 32 + 16 + r15) * 72 + ks * 32 + g * 8);
            #pragma unroll
            for (int m = 0; m < 4; ++m) {
                short8 af = *(const short8*)(As + (m * 16 + r15) * 72 + ks * 32 + g * 8);
                acc[m][0] = mfma16(af, bf0, acc[m][0]);
                acc[m][1] = mfma16(af, bf1, acc[m][1]);
            }
        }
    }
    __syncthreads();                     // all As/Bs reads complete before Ct overwrite
    #pragma unroll
    for (int n = 0; n < 2; ++n)
        #pragma unroll
        for (int m = 0; m < 4; ++m)
            #pragma unroll
            for (int r = 0; r < 4; ++r) {
                int s = m * 16 + g * 4 + r;
                if (s < 56) Ct[(w * 32 + n * 16 + r15) * 58 + s] = acc[m][n][r];
            }
    __syncthreads();
    float sum = 0.f, ss = 0.f;
    for (int idx = tid; idx < 128 * 56; idx += 256) {
        int col = idx / 56, s = idx - col * 56, px = px0 + s;
        if (px < 196) {
            float v = Ct[col * 58 + s] * kscale;
            __hip_bfloat16 hv = __float2bfloat16(v);
            float vq = __bfloat162float(hv);
            pg[(size_t)(coQ + col) * 196 + px] = hv;
            sum += vq; ss += vq * vq;    // stats over exactly what gn_apply will read
        }
    }
    rs[tid] = sum; rss[tid] = ss;
    __syncthreads();
    for (int st = 128; st > 0; st >>= 1) {
        if (tid < st) { rs[tid] += rs[tid + st]; rss[tid] += rss[tid + st]; }
        __syncthreads();
    }
    if (tid == 0) {
        float* gns = (float*)(wsb + BO_GNS);
        gns[gslot * 2] = rs[0];
        gns[gslot * 2 + 1] = rss[0];
    }
}

// ---------------- gn_apply: bf16 pre-GN + residual -> f32 d_out ----------------
__global__ __launch_bounds__(256) void gn_apply(
        const char* __restrict__ wsb, const float* __restrict__ x,
        const float* __restrict__ gg, const float* __restrict__ gb,
        float* __restrict__ out) {
    int bgid = blockIdx.x >> 4, six = blockIdx.x & 15;
    int g = bgid & 3;
    const float* gns = (const float*)(wsb + BO_GNS);
    float S = 0.f, Q = 0.f;
    #pragma unroll
    for (int k = 0; k < 8; ++k) { S += gns[(bgid * 8 + k) * 2]; Q += gns[(bgid * 8 + k) * 2 + 1]; }
    float mu = S * (1.f / 50176.f);
    float var = Q * (1.f / 50176.f) - mu * mu;
    float rstd = rsqrtf(var + EPSN);

    const __hip_bfloat16* pg = (const __hip_bfloat16*)(wsb + BO_XQ) + (size_t)bgid * 50176;
    const float* xg = x + (size_t)bgid * 50176;
    float* og = out + (size_t)bgid * 50176;

    int tid = threadIdx.x;
    for (int i = tid; i < 392; i += 256) {           // 3136 elems per section, 8/thread
        int eb = six * 3136 + i * 8;
        int c = eb / 196, r = eb - c * 196;
        short8 hv = *(const short8*)(pg + eb);
        float4 x0 = *(const float4*)(xg + eb);
        float4 x1 = *(const float4*)(xg + eb + 4);
        float xv[8] = {x0.x, x0.y, x0.z, x0.w, x1.x, x1.y, x1.z, x1.w};
        float o[8];
        #pragma unroll
        for (int j = 0; j < 8; ++j) {
            int gc = g * 256 + c;
            float sc = gg[gc] * rstd;
            float sh = gb[gc] - mu * sc;
            float v = bf16s_to_f32(hv[j]);
            o[j] = fmaxf(v * sc + sh + xv[j], 0.f);
            if (++r == 196) { r = 0; ++c; }
        }
        *(float4*)(og + eb)     = make_float4(o[0], o[1], o[2], o[3]);
        *(float4*)(og + eb + 4) = make_float4(o[4], o[5], o[6], o[7]);
    }
}

// ---------------- launch ----------------
extern "C" void kernel_launch(void* const* d_in, const int* in_sizes, int n_in,
                              void* d_out, int out_size, void* d_ws, size_t ws_size,
                              hipStream_t stream) {
    (void)in_sizes; (void)n_in; (void)out_size; (void)ws_size;
    const float* x    = (const float*)d_in[0];
    const int*   mask = (const int*)d_in[1];
    const float* w1   = (const float*)d_in[2];
    const float* w2   = (const float*)d_in[3];
    const float* w3   = (const float*)d_in[4];
    const float* b1g  = (const float*)d_in[5];
    const float* b1b  = (const float*)d_in[6];
    const float* b1m  = (const float*)d_in[7];
    const float* b1v  = (const float*)d_in[8];
    const float* b2g  = (const float*)d_in[9];
    const float* b2b  = (const float*)d_in[10];
    const float* b2m  = (const float*)d_in[11];
    const float* b2v  = (const float*)d_in[12];
    const float* gng  = (const float*)d_in[13];
    const float* gnb  = (const float*)d_in[14];
    char* wsb = (char*)d_ws;
    char* doutb = (char*)d_out;
    float* out = (float*)d_out;

    maxabs_kernel<<<144, 1024, 0, stream>>>(w1, w2, w3, (float*)(wsb + BO_PMAX));
    prep_all<<<4864, 256, 0, stream>>>(w1, w2, w3, x, mask, wsb, doutb);
    conv1_mfma<<<dim3(4, 4, 32), 256, 0, stream>>>(wsb, mask, b1g, b1b, b1m, b1v);
    conv2_mfma<<<dim3(2, 4, 32), 256, 0, stream>>>(wsb, doutb, mask, b2g, b2b, b2m, b2v);
    conv3_mfma<<<dim3(4, 8, 32), 256, 0, stream>>>(wsb, doutb, mask);
    gn_apply<<<2048, 256, 0, stream>>>(wsb, x, gng, gnb, out);
}